// Round 8
// baseline (1082.834 us; speedup 1.0000x reference)
//
#include <hip/hip_runtime.h>
#include <hip/hip_bf16.h>

#define EMB   1024
#define HID   1024
#define NBATCH 64
#define SEQ   128
#define NGATE 4096   // 4*HID
#define NBLK  128    // recurrence grid (each block owns 8 hidden units)

typedef __attribute__((ext_vector_type(8))) short bf16x8;
typedef __attribute__((ext_vector_type(4))) float f32x4;

__device__ __forceinline__ unsigned short f2bf(float f) {
    unsigned int u = __float_as_uint(f);
    unsigned int r = (u + 0x7FFFu + ((u >> 16) & 1u)) >> 16;
    return (unsigned short)r;
}

__device__ __forceinline__ float bf2f(unsigned short s) {
    return __uint_as_float(((unsigned int)s) << 16);
}

__device__ __forceinline__ bf16x8 pack8(float4 a, float4 b) {
    bf16x8 r;
    r[0] = (short)f2bf(a.x); r[1] = (short)f2bf(a.y);
    r[2] = (short)f2bf(a.z); r[3] = (short)f2bf(a.w);
    r[4] = (short)f2bf(b.x); r[5] = (short)f2bf(b.y);
    r[6] = (short)f2bf(b.z); r[7] = (short)f2bf(b.w);
    return r;
}

__device__ __forceinline__ float sigmoidf_(float x) { return 1.0f / (1.0f + __expf(-x)); }
__device__ __forceinline__ float tanhf_(float x)    { return 1.0f - 2.0f / (1.0f + __expf(2.0f * x)); }

// ---- prep kernels ------------------------------------------------------

// X[t*64+b][k] = bf16(emb[inputs[b][t]][k]);  grid 8192, block 256
__global__ void gather_x(const float* __restrict__ emb, const int* __restrict__ inp,
                         unsigned short* __restrict__ xbf) {
    int m = blockIdx.x;          // m = t*64 + b
    int t = m >> 6, b = m & 63;
    int tok = inp[b * SEQ + t];
    float4 v = ((const float4*)(emb + (long)tok * EMB))[threadIdx.x];
    ushort4 o;
    o.x = f2bf(v.x); o.y = f2bf(v.y); o.z = f2bf(v.z); o.w = f2bf(v.w);
    ((ushort4*)(xbf + (long)m * EMB))[threadIdx.x] = o;
}

// W_ih -> bf16; grid 4096, block 256
__global__ void conv_w(const float* __restrict__ w, unsigned short* __restrict__ wbf) {
    long i = (long)blockIdx.x * 1024 + (long)threadIdx.x * 4;
    float4 v = *(const float4*)(w + i);
    ushort4 o;
    o.x = f2bf(v.x); o.y = f2bf(v.y); o.z = f2bf(v.z); o.w = f2bf(v.w);
    *(ushort4*)(wbf + i) = o;
}

// bsum = b_ih + b_hh; grid 16, block 256
__global__ void bsum_k(const float* __restrict__ bi, const float* __restrict__ bh,
                       float* __restrict__ bs) {
    int i = blockIdx.x * 256 + threadIdx.x;
    bs[i] = bi[i] + bh[i];
}

// ---- input GEMM: XWb[t][n][b] = bf16(sum_k X[t*64+b][k]*W_ih[n][k] + bsum[n]) ----
__global__ __launch_bounds__(256) void gemm_xw(const unsigned short* __restrict__ A,
                                               const unsigned short* __restrict__ Bw,
                                               const float* __restrict__ bsum,
                                               unsigned short* __restrict__ XWb) {
    __shared__ unsigned short As[128][40];
    __shared__ unsigned short Bs[128][40];
    int bx = blockIdx.x;             // N tile (0..31)
    int by = blockIdx.y;             // M tile (0..63)
    int tid = threadIdx.x;
    int w = tid >> 6, l = tid & 63;
    int wm = w >> 1, wn = w & 1;
    int lr = l & 15, lk = l >> 4;

    f32x4 acc[4][4];
#pragma unroll
    for (int ni = 0; ni < 4; ++ni) {
        float bsv = bsum[bx * 128 + wn * 64 + ni * 16 + lr];
#pragma unroll
        for (int mi = 0; mi < 4; ++mi) {
            acc[mi][ni][0] = bsv; acc[mi][ni][1] = bsv;
            acc[mi][ni][2] = bsv; acc[mi][ni][3] = bsv;
        }
    }

    int sr = tid >> 1;
    int sc = (tid & 1) * 16;
    const unsigned short* ga = A  + (long)(by * 128 + sr) * 1024 + sc;
    const unsigned short* gb = Bw + (long)(bx * 128 + sr) * 1024 + sc;

    for (int kt = 0; kt < 32; ++kt) {
        uint4 va0 = *(const uint4*)(ga);
        uint4 va1 = *(const uint4*)(ga + 8);
        uint4 vb0 = *(const uint4*)(gb);
        uint4 vb1 = *(const uint4*)(gb + 8);
        *(uint4*)&As[sr][sc]     = va0;
        *(uint4*)&As[sr][sc + 8] = va1;
        *(uint4*)&Bs[sr][sc]     = vb0;
        *(uint4*)&Bs[sr][sc + 8] = vb1;
        __syncthreads();

        bf16x8 af[4], bfr[4];
#pragma unroll
        for (int mi = 0; mi < 4; ++mi)
            af[mi] = *(const bf16x8*)&As[wm * 64 + mi * 16 + lr][lk * 8];
#pragma unroll
        for (int ni = 0; ni < 4; ++ni)
            bfr[ni] = *(const bf16x8*)&Bs[wn * 64 + ni * 16 + lr][lk * 8];
#pragma unroll
        for (int mi = 0; mi < 4; ++mi)
#pragma unroll
            for (int ni = 0; ni < 4; ++ni)
                acc[mi][ni] = __builtin_amdgcn_mfma_f32_16x16x32_bf16(af[mi], bfr[ni], acc[mi][ni], 0, 0, 0);
        __syncthreads();
        ga += 32; gb += 32;
    }

#pragma unroll
    for (int mi = 0; mi < 4; ++mi) {
        int mg = by * 128 + wm * 64 + mi * 16 + lk * 4;
        int tt = mg >> 6;
        int bb = mg & 63;
#pragma unroll
        for (int ni = 0; ni < 4; ++ni) {
            int nn = bx * 128 + wn * 64 + ni * 16 + lr;
            ushort4 o;
            o.x = f2bf(acc[mi][ni][0]); o.y = f2bf(acc[mi][ni][1]);
            o.z = f2bf(acc[mi][ni][2]); o.w = f2bf(acc[mi][ni][3]);
            *(ushort4*)(XWb + (long)tt * (NGATE * 64) + (long)nn * 64 + bb) = o;
        }
    }
}

// ---- recurrence: 128 blocks x 512 thr, fresh-slot exchange -------------
// Block g owns hid units g*8..g*8+7 (32 gate rows). 8 waves = 4 batch-groups
// x 2 gate-groups. h slot layout per step (128KB, stride 16384 ULLs):
//   [g:128][b:64][u:8] bf16 -> chunk g is 1KB contiguous; a reader's
//   A-fragment (8 consecutive hid of one batch) is ONE 16B uint4.
// hseq is a VIRGIN region (never cached-read before its agent-store within
// a call) -> no stale-L2 hazard for the flag-gated cached reads.
// Exchange: agent stores -> issue poll load -> vmcnt(1) (stores ack'd,
// poll flying) -> publish flag -> vmcnt(0) -> check. XW values for step
// t+1 are prefetched during the exchange idle.
__global__ __launch_bounds__(512) void lstm_rec(const float* __restrict__ Whh,
                                                const unsigned short* __restrict__ XWb,
                                                unsigned short* __restrict__ hseq,
                                                unsigned* __restrict__ flags,
                                                float* __restrict__ out) {
    __shared__ float Glds[32][68];              // [n_local][batch]
    __shared__ unsigned short Hs[64][8];        // h pack: [batch][u]

    int tid = threadIdx.x;
    int w = tid >> 6, l = tid & 63;             // wave, lane
    int lr = l & 15, lk = l >> 4;
    int bg = w & 3, ng = w >> 2;                // batch-group, gate-group
    int g = blockIdx.x;                         // owns hid g*8..g*8+7

    // W_hh fragment preload: lane lr holds gate col n_local = ng*16+lr
    int nl = ng * 16 + lr;
    int q = nl >> 3, u = nl & 7;
    long nrow = (long)(q * 1024 + g * 8 + u) * 1024;
    bf16x8 wf[32];
#pragma unroll
    for (int kk = 0; kk < 32; ++kk) {
        int k0 = kk * 32 + lk * 8;
        float4 w0 = *(const float4*)(Whh + nrow + k0);
        float4 w1 = *(const float4*)(Whh + nrow + k0 + 4);
        wf[kk] = pack8(w0, w1);
    }

    float c = 0.0f;
    int brow = bg * 16 + lr;                    // batch row for A-fragments

    // prefetch XW gate values for t=0 (bf16): thread (b=l, j=w)
    unsigned short pxr[4];
#pragma unroll
    for (int qq = 0; qq < 4; ++qq)
        pxr[qq] = XWb[(long)(qq * 1024 + g * 8 + w) * 64 + l];

    for (int t = 0; t < SEQ; ++t) {
        const uint4* hc = (const uint4*)hseq + (long)t * 8192;  // slot t

        // MFMA: wave (bg,ng) -> batches bg*16.. x gate cols ng*16..
        // frag kk: producing block g' = kk*4+lk; one uint4 = 8 hid of brow
        f32x4 acc0 = {0.f, 0.f, 0.f, 0.f}, acc1 = {0.f, 0.f, 0.f, 0.f};
#pragma unroll
        for (int kk = 0; kk < 32; kk += 2) {
            union { uint4 u4; bf16x8 v; } ua, ub;
            ua.u4 = hc[(kk * 4 + lk) * 64 + brow];
            ub.u4 = hc[((kk + 1) * 4 + lk) * 64 + brow];
            acc0 = __builtin_amdgcn_mfma_f32_16x16x32_bf16(ua.v, wf[kk],     acc0, 0, 0, 0);
            acc1 = __builtin_amdgcn_mfma_f32_16x16x32_bf16(ub.v, wf[kk + 1], acc1, 0, 0, 0);
        }
        f32x4 gacc = acc0 + acc1;
        // D: col(n)=lr, row(batch)=lk*4+r -> Glds[ng*16+lr][bg*16+lk*4+r]
        *(f32x4*)&Glds[ng * 16 + lr][bg * 16 + lk * 4] = gacc;
        __syncthreads();

        // activation: thread owns batch b=l, hid unit g*8+w (px prefetched)
        float p[4];
#pragma unroll
        for (int qq = 0; qq < 4; ++qq)
            p[qq] = Glds[qq * 8 + w][l] + bf2f(pxr[qq]);
        float ig = sigmoidf_(p[0]);
        float fg = sigmoidf_(p[1]);
        float gg = tanhf_(p[2]);
        float og = sigmoidf_(p[3]);
        c = fg * c + ig * gg;
        float h = og * tanhf_(c);

        if (t == SEQ - 1) {
            out[l * HID + g * 8 + w] = h;
            out[NBATCH * HID + l * HID + g * 8 + w] = c;
        } else {
            Hs[l][w] = f2bf(h);
            __syncthreads();

            // prefetch XW for step t+1 (completes during exchange idle)
#pragma unroll
            for (int qq = 0; qq < 4; ++qq)
                pxr[qq] = XWb[(long)(t + 1) * (NGATE * 64) +
                              (long)(qq * 1024 + g * 8 + w) * 64 + l];

            unsigned tv = (unsigned)(t + 1);
            if (tid < 64) {   // wave 0: store 1KB chunk, overlap ack+poll
                unsigned long long* hn = (unsigned long long*)hseq +
                                         (long)(t + 1) * 16384 + (long)g * 128;
                const unsigned long long* hsu = (const unsigned long long*)Hs;
                __hip_atomic_store(&hn[tid * 2],     hsu[tid * 2],
                                   __ATOMIC_RELAXED, __HIP_MEMORY_SCOPE_AGENT);
                __hip_atomic_store(&hn[tid * 2 + 1], hsu[tid * 2 + 1],
                                   __ATOMIC_RELAXED, __HIP_MEMORY_SCOPE_AGENT);
                if (tid < 32) {
                    const unsigned* fp = flags + tid * 4;
                    uint4 fv;
                    // first poll load issued BEFORE the store-ack wait
                    asm volatile("global_load_dwordx4 %0, %1, off sc0 sc1"
                                 : "=v"(fv) : "v"(fp) : "memory");
                    // stores (and older px loads) ack'd; poll still flying
                    asm volatile("s_waitcnt vmcnt(1)" ::: "memory");
                    if (tid == 0)
                        __hip_atomic_store(&flags[g], tv,
                                           __ATOMIC_RELAXED, __HIP_MEMORY_SCOPE_AGENT);
                    asm volatile("s_waitcnt vmcnt(0)" ::: "memory");
                    __builtin_amdgcn_sched_barrier(0);
                    long spins = 0;
                    for (;;) {
                        unsigned mn = fv.x < fv.y ? fv.x : fv.y;
                        unsigned mn2 = fv.z < fv.w ? fv.z : fv.w;
                        if (mn2 < mn) mn = mn2;
                        if (mn >= tv) break;
                        if (++spins > 500000L) break;
                        __builtin_amdgcn_s_sleep(1);
                        asm volatile("global_load_dwordx4 %0, %1, off sc0 sc1\n\t"
                                     "s_waitcnt vmcnt(0)"
                                     : "=v"(fv) : "v"(fp) : "memory");
                        __builtin_amdgcn_sched_barrier(0);
                    }
                } else {
                    // lanes 32-63: just drain own stores before the barrier
                    asm volatile("s_waitcnt vmcnt(0)" ::: "memory");
                }
            }
            __syncthreads();            // all waves gated on wave 0's poll exit
        }
    }
}

// ---- launch ------------------------------------------------------------
extern "C" void kernel_launch(void* const* d_in, const int* in_sizes, int n_in,
                              void* d_out, int out_size, void* d_ws, size_t ws_size,
                              hipStream_t stream) {
    const float* emb  = (const float*)d_in[0];
    const float* W_ih = (const float*)d_in[1];
    const float* W_hh = (const float*)d_in[2];
    const float* b_ih = (const float*)d_in[3];
    const float* b_hh = (const float*)d_in[4];
    const int*   inp  = (const int*)d_in[5];
    float* out = (float*)d_out;

    // workspace layout (~104 MiB used; hseq is its OWN region, no alias)
    char* ws = (char*)d_ws;
    unsigned short* XWb  = (unsigned short*)ws;                   //  67,108,864 B
    unsigned short* Xbf  = (unsigned short*)(ws + 67108864);      //  16,777,216 B
    unsigned short* Wbf  = (unsigned short*)(ws + 83886080);      //   8,388,608 B
    float*          bs   = (float*)(ws + 92274688);               //      16,384 B
    unsigned short* hseq = (unsigned short*)(ws + 92291072);      //  16,777,216 B
    unsigned*       flags= (unsigned*)(ws + 109068288);           //         512 B

    hipMemsetAsync(flags, 0, NBLK * sizeof(unsigned), stream);
    hipMemsetAsync(hseq, 0, NBATCH * HID * sizeof(unsigned short), stream);  // slot 0
    gather_x<<<SEQ * NBATCH, 256, 0, stream>>>(emb, inp, Xbf);
    conv_w<<<NGATE, 256, 0, stream>>>(W_ih, Wbf);
    bsum_k<<<16, 256, 0, stream>>>(b_ih, b_hh, bs);
    gemm_xw<<<dim3(32, 64), 256, 0, stream>>>(Xbf, Wbf, bs, XWb);
    lstm_rec<<<NBLK, 512, 0, stream>>>(W_hh, XWb, hseq, flags, out);
}

// Round 10
// 1082.159 us; speedup vs baseline: 1.0006x; 1.0006x over previous
//
#include <hip/hip_runtime.h>
#include <hip/hip_bf16.h>

#define EMB   1024
#define HID   1024
#define NBATCH 64
#define SEQ   128
#define NGATE 4096   // 4*HID
#define NBLK  128    // recurrence grid (each block owns 8 hidden units)

typedef __attribute__((ext_vector_type(8))) short bf16x8;
typedef __attribute__((ext_vector_type(4))) float f32x4;

__device__ __forceinline__ unsigned short f2bf(float f) {
    unsigned int u = __float_as_uint(f);
    unsigned int r = (u + 0x7FFFu + ((u >> 16) & 1u)) >> 16;
    return (unsigned short)r;
}

__device__ __forceinline__ float bf2f(unsigned short s) {
    return __uint_as_float(((unsigned int)s) << 16);
}

__device__ __forceinline__ bf16x8 pack8(float4 a, float4 b) {
    bf16x8 r;
    r[0] = (short)f2bf(a.x); r[1] = (short)f2bf(a.y);
    r[2] = (short)f2bf(a.z); r[3] = (short)f2bf(a.w);
    r[4] = (short)f2bf(b.x); r[5] = (short)f2bf(b.y);
    r[6] = (short)f2bf(b.z); r[7] = (short)f2bf(b.w);
    return r;
}

__device__ __forceinline__ float sigmoidf_(float x) { return 1.0f / (1.0f + __expf(-x)); }
__device__ __forceinline__ float tanhf_(float x)    { return 1.0f - 2.0f / (1.0f + __expf(2.0f * x)); }

// ---- prep kernels ------------------------------------------------------

// X[t*64+b][k] = bf16(emb[inputs[b][t]][k]);  grid 8192, block 256
__global__ void gather_x(const float* __restrict__ emb, const int* __restrict__ inp,
                         unsigned short* __restrict__ xbf) {
    int m = blockIdx.x;          // m = t*64 + b
    int t = m >> 6, b = m & 63;
    int tok = inp[b * SEQ + t];
    float4 v = ((const float4*)(emb + (long)tok * EMB))[threadIdx.x];
    ushort4 o;
    o.x = f2bf(v.x); o.y = f2bf(v.y); o.z = f2bf(v.z); o.w = f2bf(v.w);
    ((ushort4*)(xbf + (long)m * EMB))[threadIdx.x] = o;
}

// W_ih -> bf16; grid 4096, block 256
__global__ void conv_w(const float* __restrict__ w, unsigned short* __restrict__ wbf) {
    long i = (long)blockIdx.x * 1024 + (long)threadIdx.x * 4;
    float4 v = *(const float4*)(w + i);
    ushort4 o;
    o.x = f2bf(v.x); o.y = f2bf(v.y); o.z = f2bf(v.z); o.w = f2bf(v.w);
    *(ushort4*)(wbf + i) = o;
}

// bsum = b_ih + b_hh; grid 16, block 256
__global__ void bsum_k(const float* __restrict__ bi, const float* __restrict__ bh,
                       float* __restrict__ bs) {
    int i = blockIdx.x * 256 + threadIdx.x;
    bs[i] = bi[i] + bh[i];
}

// ---- input GEMM: XWb[t][n][b] = bf16(sum_k X[t*64+b][k]*W_ih[n][k] + bsum[n]) ----
__global__ __launch_bounds__(256) void gemm_xw(const unsigned short* __restrict__ A,
                                               const unsigned short* __restrict__ Bw,
                                               const float* __restrict__ bsum,
                                               unsigned short* __restrict__ XWb) {
    __shared__ unsigned short As[128][40];
    __shared__ unsigned short Bs[128][40];
    int bx = blockIdx.x;             // N tile (0..31)
    int by = blockIdx.y;             // M tile (0..63)
    int tid = threadIdx.x;
    int w = tid >> 6, l = tid & 63;
    int wm = w >> 1, wn = w & 1;
    int lr = l & 15, lk = l >> 4;

    f32x4 acc[4][4];
#pragma unroll
    for (int ni = 0; ni < 4; ++ni) {
        float bsv = bsum[bx * 128 + wn * 64 + ni * 16 + lr];
#pragma unroll
        for (int mi = 0; mi < 4; ++mi) {
            acc[mi][ni][0] = bsv; acc[mi][ni][1] = bsv;
            acc[mi][ni][2] = bsv; acc[mi][ni][3] = bsv;
        }
    }

    int sr = tid >> 1;
    int sc = (tid & 1) * 16;
    const unsigned short* ga = A  + (long)(by * 128 + sr) * 1024 + sc;
    const unsigned short* gb = Bw + (long)(bx * 128 + sr) * 1024 + sc;

    for (int kt = 0; kt < 32; ++kt) {
        uint4 va0 = *(const uint4*)(ga);
        uint4 va1 = *(const uint4*)(ga + 8);
        uint4 vb0 = *(const uint4*)(gb);
        uint4 vb1 = *(const uint4*)(gb + 8);
        *(uint4*)&As[sr][sc]     = va0;
        *(uint4*)&As[sr][sc + 8] = va1;
        *(uint4*)&Bs[sr][sc]     = vb0;
        *(uint4*)&Bs[sr][sc + 8] = vb1;
        __syncthreads();

        bf16x8 af[4], bfr[4];
#pragma unroll
        for (int mi = 0; mi < 4; ++mi)
            af[mi] = *(const bf16x8*)&As[wm * 64 + mi * 16 + lr][lk * 8];
#pragma unroll
        for (int ni = 0; ni < 4; ++ni)
            bfr[ni] = *(const bf16x8*)&Bs[wn * 64 + ni * 16 + lr][lk * 8];
#pragma unroll
        for (int mi = 0; mi < 4; ++mi)
#pragma unroll
            for (int ni = 0; ni < 4; ++ni)
                acc[mi][ni] = __builtin_amdgcn_mfma_f32_16x16x32_bf16(af[mi], bfr[ni], acc[mi][ni], 0, 0, 0);
        __syncthreads();
        ga += 32; gb += 32;
    }

#pragma unroll
    for (int mi = 0; mi < 4; ++mi) {
        int mg = by * 128 + wm * 64 + mi * 16 + lk * 4;
        int tt = mg >> 6;
        int bb = mg & 63;
#pragma unroll
        for (int ni = 0; ni < 4; ++ni) {
            int nn = bx * 128 + wn * 64 + ni * 16 + lr;
            ushort4 o;
            o.x = f2bf(acc[mi][ni][0]); o.y = f2bf(acc[mi][ni][1]);
            o.z = f2bf(acc[mi][ni][2]); o.w = f2bf(acc[mi][ni][3]);
            *(ushort4*)(XWb + (long)tt * (NGATE * 64) + (long)nn * 64 + bb) = o;
        }
    }
}

// ---- recurrence: 128 blocks x 512 thr, fresh-slot exchange -------------
// Block g owns hid units g*8..g*8+7 (32 gate rows). 8 waves = 4 batch-groups
// x 2 gate-groups. h slot per step: 128KB, layout [g:128][b:64][u:8] bf16;
// chunk g is 1KB contiguous; a reader's A-fragment (8 consecutive hid of one
// batch) is ONE 16B uint4. hseq is a virgin region (never cached-read before
// its agent-store within a call) -> no stale-L2 hazard for cached reads.
// Exchange critical path kept CLEAN: the only VMEM ops outstanding at the
// vmcnt(0) before the flag publish are wave 0's two 8B h-chunk stores.
// XW prefetch for step t+1 is issued AFTER the publish (wave 0) / during
// wave 0's exchange (waves 1-7), so it never gates the publish chain.
__global__ __launch_bounds__(512) void lstm_rec(const float* __restrict__ Whh,
                                                const unsigned short* __restrict__ XWb,
                                                unsigned short* __restrict__ hseq,
                                                unsigned* __restrict__ flags,
                                                float* __restrict__ out) {
    __shared__ float Glds[32][68];              // [n_local][batch]
    __shared__ unsigned short Hs[64][8];        // h pack: [batch][u]

    int tid = threadIdx.x;
    int w = tid >> 6, l = tid & 63;             // wave, lane
    int lr = l & 15, lk = l >> 4;
    int bg = w & 3, ng = w >> 2;                // batch-group, gate-group
    int g = blockIdx.x;                         // owns hid g*8..g*8+7

    // W_hh fragment preload: lane lr holds gate col n_local = ng*16+lr
    int nl = ng * 16 + lr;
    int q = nl >> 3, u = nl & 7;
    long nrow = (long)(q * 1024 + g * 8 + u) * 1024;
    bf16x8 wf[32];
#pragma unroll
    for (int kk = 0; kk < 32; ++kk) {
        int k0 = kk * 32 + lk * 8;
        float4 w0 = *(const float4*)(Whh + nrow + k0);
        float4 w1 = *(const float4*)(Whh + nrow + k0 + 4);
        wf[kk] = pack8(w0, w1);
    }

    float c = 0.0f;
    int brow = bg * 16 + lr;                    // batch row for A-fragments

    // px pipeline: pxr holds this step's XW gate values (thread: b=l, j=w)
    unsigned short pxr[4];
#pragma unroll
    for (int qq = 0; qq < 4; ++qq)
        pxr[qq] = XWb[(long)(qq * 1024 + g * 8 + w) * 64 + l];

    for (int t = 0; t < SEQ; ++t) {
        const uint4* hc = (const uint4*)hseq + (long)t * 8192;  // slot t

        // MFMA: wave (bg,ng) -> batches bg*16.. x gate cols ng*16..
        // frag kk: producing block g' = kk*4+lk; one uint4 = 8 hid of brow
        f32x4 acc0 = {0.f, 0.f, 0.f, 0.f}, acc1 = {0.f, 0.f, 0.f, 0.f};
#pragma unroll
        for (int kk = 0; kk < 32; kk += 2) {
            union { uint4 u4; bf16x8 v; } ua, ub;
            ua.u4 = hc[(kk * 4 + lk) * 64 + brow];
            ub.u4 = hc[((kk + 1) * 4 + lk) * 64 + brow];
            acc0 = __builtin_amdgcn_mfma_f32_16x16x32_bf16(ua.v, wf[kk],     acc0, 0, 0, 0);
            acc1 = __builtin_amdgcn_mfma_f32_16x16x32_bf16(ub.v, wf[kk + 1], acc1, 0, 0, 0);
        }
        f32x4 gacc = acc0 + acc1;
        // D: col(n)=lr, row(batch)=lk*4+r -> Glds[ng*16+lr][bg*16+lk*4+r]
        *(f32x4*)&Glds[ng * 16 + lr][bg * 16 + lk * 4] = gacc;
        __syncthreads();

        // activation: thread owns batch b=l, hid unit g*8+w (px prefetched)
        float p[4];
#pragma unroll
        for (int qq = 0; qq < 4; ++qq)
            p[qq] = Glds[qq * 8 + w][l] + bf2f(pxr[qq]);
        float ig = sigmoidf_(p[0]);
        float fg = sigmoidf_(p[1]);
        float gg = tanhf_(p[2]);
        float og = sigmoidf_(p[3]);
        c = fg * c + ig * gg;
        float h = og * tanhf_(c);

        if (t == SEQ - 1) {
            out[l * HID + g * 8 + w] = h;
            out[NBATCH * HID + l * HID + g * 8 + w] = c;
        } else {
            Hs[l][w] = f2bf(h);
            __syncthreads();
            unsigned tv = (unsigned)(t + 1);
            long xwoff = (long)(t + 1) * (NGATE * 64) + (long)(g * 8 + w) * 64 + l;

            if (w == 0) {   // wave 0: clean store->ack->publish->poll chain
                unsigned long long* hn = (unsigned long long*)hseq +
                                         (long)(t + 1) * 16384 + (long)g * 128;
                const unsigned long long* hsu = (const unsigned long long*)Hs;
                __hip_atomic_store(&hn[l * 2],     hsu[l * 2],
                                   __ATOMIC_RELAXED, __HIP_MEMORY_SCOPE_AGENT);
                __hip_atomic_store(&hn[l * 2 + 1], hsu[l * 2 + 1],
                                   __ATOMIC_RELAXED, __HIP_MEMORY_SCOPE_AGENT);
                asm volatile("s_waitcnt vmcnt(0)" ::: "memory");  // ONLY the 2 stores
                if (l == 0)
                    __hip_atomic_store(&flags[g], tv,
                                       __ATOMIC_RELAXED, __HIP_MEMORY_SCOPE_AGENT);
                if (l < 32) {
                    const unsigned* fp = flags + l * 4;
                    long spins = 0;
                    for (;;) {
                        uint4 fv;
                        asm volatile("global_load_dwordx4 %0, %1, off sc0 sc1\n\t"
                                     "s_waitcnt vmcnt(0)"
                                     : "=v"(fv) : "v"(fp) : "memory");
                        __builtin_amdgcn_sched_barrier(0);
                        unsigned mn  = fv.x < fv.y ? fv.x : fv.y;
                        unsigned mn2 = fv.z < fv.w ? fv.z : fv.w;
                        if (mn2 < mn) mn = mn2;
                        if (mn >= tv) break;
                        if (++spins > 500000L) break;
                        __builtin_amdgcn_s_sleep(1);
                    }
                }
                // px prefetch AFTER publish/poll: flies during next MFMA phase
#pragma unroll
                for (int qq = 0; qq < 4; ++qq)
                    pxr[qq] = XWb[xwoff + (long)qq * (1024 * 64)];
            } else {
                // waves 1-7: prefetch during wave 0's exchange, then wait
#pragma unroll
                for (int qq = 0; qq < 4; ++qq)
                    pxr[qq] = XWb[xwoff + (long)qq * (1024 * 64)];
            }
            __syncthreads();            // all waves gated on wave 0's poll exit
        }
    }
}

// ---- launch ------------------------------------------------------------
extern "C" void kernel_launch(void* const* d_in, const int* in_sizes, int n_in,
                              void* d_out, int out_size, void* d_ws, size_t ws_size,
                              hipStream_t stream) {
    const float* emb  = (const float*)d_in[0];
    const float* W_ih = (const float*)d_in[1];
    const float* W_hh = (const float*)d_in[2];
    const float* b_ih = (const float*)d_in[3];
    const float* b_hh = (const float*)d_in[4];
    const int*   inp  = (const int*)d_in[5];
    float* out = (float*)d_out;

    // workspace layout (~104 MiB used; hseq is its OWN virgin region)
    char* ws = (char*)d_ws;
    unsigned short* XWb  = (unsigned short*)ws;                   //  67,108,864 B
    unsigned short* Xbf  = (unsigned short*)(ws + 67108864);      //  16,777,216 B
    unsigned short* Wbf  = (unsigned short*)(ws + 83886080);      //   8,388,608 B
    float*          bs   = (float*)(ws + 92274688);               //      16,384 B
    unsigned short* hseq = (unsigned short*)(ws + 92291072);      //  16,777,216 B
    unsigned*       flags= (unsigned*)(ws + 109068288);           //         512 B

    hipMemsetAsync(flags, 0, NBLK * sizeof(unsigned), stream);
    hipMemsetAsync(hseq, 0, NBATCH * HID * sizeof(unsigned short), stream);  // slot 0
    gather_x<<<SEQ * NBATCH, 256, 0, stream>>>(emb, inp, Xbf);
    conv_w<<<NGATE, 256, 0, stream>>>(W_ih, Wbf);
    bsum_k<<<16, 256, 0, stream>>>(b_ih, b_hh, bs);
    gemm_xw<<<dim3(32, 64), 256, 0, stream>>>(Xbf, Wbf, bs, XWb);
    lstm_rec<<<NBLK, 512, 0, stream>>>(W_hh, XWb, hseq, flags, out);
}